// Round 2
// baseline (364.461 us; speedup 1.0000x reference)
//
#include <hip/hip_runtime.h>

#define CIN 64
#define OC 128
#define HW 112
#define HWHW (HW*HW)          // 12544
#define NIMG 32

// ws layout (elems of bf16/ushort):
//   [0, XN_ELEMS): x_nhwc bf16  [32][112][112][64]
//   [WT_OFF_EL, +73728): weights bf16, layout [tap][k-half][128 o][32 c]
#define XN_ELEMS (NIMG*HWHW*CIN)        // 25,690,112
#define WT_OFF_EL (XN_ELEMS + 128)

#define ROWE (114*64)                   // LDS row slot: 114 cols (+-1 pad) x 64c
#define NSLOT 5                         // 5-slot ring: 72,960 B -> 2 blocks/CU

typedef __attribute__((ext_vector_type(8))) short short8;
typedef __attribute__((ext_vector_type(4))) float floatx4;

__device__ inline unsigned short f2bf(float f) {
    unsigned u = __float_as_uint(f);
    u += 0x7fffu + ((u >> 16) & 1u);   // RNE
    return (unsigned short)(u >> 16);
}

__device__ inline void async16(const unsigned short* g, unsigned short* l) {
    __builtin_amdgcn_global_load_lds(
        (const __attribute__((address_space(1))) void*)g,
        (__attribute__((address_space(3))) void*)l, 16, 0, 0);
}

// ---- Pre-pass (merged): x NCHW fp32 -> NHWC bf16, and weight repack ----
__global__ __launch_bounds__(256) void xform(const float* __restrict__ x,
                                             const float* __restrict__ wgt,
                                             unsigned short* __restrict__ ws16)
{
    const int tid = threadIdx.x;
    if (blockIdx.x < NIMG * HW) {
        // x part: per (n,h) row, LDS tile transpose w<->c
        __shared__ float s[HW * (CIN + 1)];
        const int n = blockIdx.x / HW;
        const int h = blockIdx.x % HW;
        const float* xp = x + (size_t)n * CIN * HWHW + h * HW;
        // float2 loads: 64c x 56 pairs = 3584, 14 iters; LDS stride 65 -> <=2-way
        for (int idx = tid; idx < CIN * 56; idx += 256) {
            const int c  = idx / 56;
            const int w2 = idx - c * 56;
            const float2 v = *(const float2*)(xp + c * HWHW + w2 * 2);
            s[(w2 * 2 + 0) * (CIN + 1) + c] = v.x;
            s[(w2 * 2 + 1) * (CIN + 1) + c] = v.y;
        }
        __syncthreads();
        unsigned short* op = ws16 + (size_t)(n * HW + h) * HW * CIN;
        for (int idx = tid; idx < (CIN * HW) / 8; idx += 256) {
            const int w  = idx >> 3;
            const int c0 = (idx & 7) * 8;
            union { unsigned short us[8]; uint4 v; } u;
            #pragma unroll
            for (int j = 0; j < 8; ++j)
                u.us[j] = f2bf(s[w * (CIN + 1) + c0 + j]);
            *(uint4*)(op + w * CIN + c0) = u.v;
        }
    } else {
        // weight part: [O][C][3][3] fp32 -> [tap][c>>5][o][c&31] bf16
        const int idx = (blockIdx.x - NIMG * HW) * 256 + tid;  // 0..73727
        const int c = idx & 63;
        const int o = (idx >> 6) & 127;
        const int t = idx >> 13;                               // 0..8
        const float v = wgt[(o * CIN + c) * 9 + t];
        ws16[WT_OFF_EL + ((size_t)(t * 2 + (c >> 5)) * 128 + o) * 32 + (c & 31)] = f2bf(v);
    }
}

// ---- cooperative row stage: all 4 waves split one image row ----
// gr == nullptr -> zero-fill (padding rows above/below image)
__device__ __forceinline__ void stage_row_all(unsigned short* rowb,
                                              const unsigned short* gr,
                                              int wave, int lane)
{
    if (gr) {
        const int grp = lane >> 3;           // col within 8-col chunk
        const int sub = lane & 7;            // c-block slot
        // stored col ws = 1+j*8+grp -> ws&7 = (1+grp)&7; slot `sub` holds
        // logical c-block sub ^ (ws&7)  (swizzle applied on GLOBAL source)
        const int swz = sub ^ ((1 + grp) & 7);
        const unsigned short* gl = gr + grp * 64 + swz * 8;
        #pragma unroll
        for (int k = 0; k < 4; ++k) {
            const int j = wave + 4 * k;      // waves 0,1: 4 chunks; 2,3: 3 chunks
            if (j < 14) async16(gl + j * 512, rowb + (1 + j * 8) * 64);
        }
        // pad columns (stored cols 0 and 113) zeroed by waves 2/3
        if (wave == 2 && lane < 8) *(uint4*)(rowb + lane * 8) = (uint4){0,0,0,0};
        if (wave == 3 && lane < 8) *(uint4*)(rowb + 113 * 64 + lane * 8) = (uint4){0,0,0,0};
    } else {
        const int t = wave * 64 + lane;
        #pragma unroll
        for (int k = 0; k < 4; ++k) {
            const int e = t + k * 256;       // 912 x 16B chunks = ROWE
            if (e < ROWE / 8) *(uint4*)(rowb + e * 8) = (uint4){0,0,0,0};
        }
    }
}

// ---- one 2-row x 128o tile of MFMAs (T = tile index 0/1 within block) ----
template<int T>
__device__ __forceinline__ void tile_compute(floatx4 acc[7][4],
    const unsigned short* __restrict__ wA, const unsigned short* sx,
    int row_idx, int lane_lo, int lane_hi, int aL)
{
    #pragma unroll
    for (int mt = 0; mt < 7; ++mt)
        #pragma unroll
        for (int ot = 0; ot < 4; ++ot)
            acc[mt][ot] = (floatx4){0.f, 0.f, 0.f, 0.f};

    // A-frags double-buffered across taps (weights are L1/L2-hot)
    short8 a[2][2][4];
    #pragma unroll
    for (int k01 = 0; k01 < 2; ++k01)
        #pragma unroll
        for (int ot = 0; ot < 4; ++ot)
            a[0][k01][ot] = *(const short8*)(wA + k01 * 4096 + ot * 512 + aL);

    #pragma unroll
    for (int tap = 0; tap < 9; ++tap) {
        const int dh = tap / 3 - 1;
        const int dw = tap % 3 - 1;
        const int cur = tap & 1, nxt = cur ^ 1;
        if (tap < 8) {
            #pragma unroll
            for (int k01 = 0; k01 < 2; ++k01)
                #pragma unroll
                for (int ot = 0; ot < 4; ++ot)
                    a[nxt][k01][ot] = *(const short8*)(
                        wA + ((tap + 1) * 2 + k01) * 4096 + ot * 512 + aL);
        }
        // LDS ring slot for absolute row (h0-1) + row_idx + 1 + dh + 2T
        int slot = row_idx + (1 + dh + 2 * T);
        if (slot >= NSLOT) slot -= NSLOT;
        const int colL = lane_lo + dw + 1;                 // stored col for mt=0
        const unsigned short* sb = sx + slot * ROWE + colL * 64;
        const int sw0 = (lane_hi ^ (colL & 7)) * 8;        // k01=0 swizzle
        const int sw1 = ((lane_hi + 4) ^ (colL & 7)) * 8;  // k01=1 swizzle

        #pragma unroll
        for (int mt = 0; mt < 7; ++mt) {
            const short8 b0 = *(const short8*)(sb + mt * 1024 + sw0);
            const short8 b1 = *(const short8*)(sb + mt * 1024 + sw1);
            #pragma unroll
            for (int ot = 0; ot < 4; ++ot)
                acc[mt][ot] = __builtin_amdgcn_mfma_f32_16x16x32_bf16(
                    a[cur][0][ot], b0, acc[mt][ot], 0, 0, 0);
            #pragma unroll
            for (int ot = 0; ot < 4; ++ot)
                acc[mt][ot] = __builtin_amdgcn_mfma_f32_16x16x32_bf16(
                    a[cur][1][ot], b1, acc[mt][ot], 0, 0, 0);
        }
    }
}

// D col = m (lane_lo), row = o_rel = lane_hi*4 + i
// PLAIN stores (revert of round-1 NT): stride-HWHW scatter relies on L2
// write-combining of the 64B segments into full lines across mt steps.
__device__ __forceinline__ void tile_store(const floatx4 acc[7][4],
    const float* __restrict__ bias, float* __restrict__ out,
    int n, int h, int o0, int lane_lo, int lane_hi)
{
    #pragma unroll
    for (int ot = 0; ot < 4; ++ot) {
        const int ob = o0 + ot * 16 + lane_hi * 4;
        const float4 bv = *(const float4*)(bias + ob);
        #pragma unroll
        for (int mt = 0; mt < 7; ++mt) {
            const int w = mt * 16 + lane_lo;
            float* op = out + ((size_t)(n * OC + ob) * HW + h) * HW + w;
            op[0]        = acc[mt][ot].x + bv.x;
            op[HWHW]     = acc[mt][ot].y + bv.y;
            op[2 * HWHW] = acc[mt][ot].z + bv.z;
            op[3 * HWHW] = acc[mt][ot].w + bv.w;
        }
    }
}

// ---- Kernel 2: implicit-GEMM MFMA, 2-tile pipelined (4 output rows/block) ----
// Block: 256 thr = 4 waves; per tile 224m(2 rows) x 128o; wave: 112m x 64o.
// LDS: 5-row ring (72,960 B, 2 blocks/CU). Schedule:
//   stage rows h0-1..h0+2 -> bar -> [stage h0+3 || compute t0] -> bar ->
//   [stage h0+4 || store t0] -> bar -> compute t1 -> store t1
__global__ __launch_bounds__(256, 2) void conv_mfma(
    const unsigned short* __restrict__ ws16,
    const float* __restrict__ bias,
    float* __restrict__ out)
{
    __shared__ unsigned short sx[NSLOT * ROWE];   // 72,960 B

    const int tid  = threadIdx.x;
    const int wave = tid >> 6;
    const int lane = tid & 63;
    const int lane_lo = lane & 15;
    const int lane_hi = lane >> 4;

    // XCD-chunked swizzle: 896 blocks = 8 x 112; consecutive q tiles (shared
    // halo rows) land on the same XCD's L2. 896 % 8 == 0 -> bijective.
    const int bid0 = blockIdx.x;
    const int bid  = (bid0 & 7) * 112 + (bid0 >> 3);
    const int n  = bid / 28;
    const int q  = bid - n * 28;
    const int h0 = q * 4;                  // 4 output rows h0..h0+3

    // ---- initial stage: rows h0-1..h0+2 -> slots 0..3 ----
    #pragma unroll
    for (int k = 0; k < 4; ++k) {
        const int hr = h0 - 1 + k;
        stage_row_all(sx + k * ROWE,
                      (hr >= 0) ? ws16 + (size_t)(n * HW + hr) * HW * CIN
                                : (const unsigned short*)nullptr,
                      wave, lane);
    }
    __syncthreads();   // drains vmcnt: slots 0..3 ready

    // prefetch row h0+3 -> slot 4; lands under tile-0 compute (h0+3 <= 111 always)
    stage_row_all(sx + 4 * ROWE, ws16 + (size_t)(n * HW + h0 + 3) * HW * CIN,
                  wave, lane);

    const unsigned short* wA = ws16 + WT_OFF_EL;
    const int row_idx = wave >> 1;          // which of the 2 output rows in a tile
    const int o0 = (wave & 1) * 64;
    const int aL = (o0 + lane_lo) * 32 + lane_hi * 8;  // lane offset in [128o][32c]

    floatx4 acc[7][4];
    tile_compute<0>(acc, wA, sx, row_idx, lane_lo, lane_hi, aL);
    __syncthreads();   // all waves done reading slot 0; stage(h0+3) drained

    // prefetch row h0+4 -> slot 0 (freed); lands under tile-0 stores
    {
        const int hr = h0 + 4;
        stage_row_all(sx + 0 * ROWE,
                      (hr < HW) ? ws16 + (size_t)(n * HW + hr) * HW * CIN
                                : (const unsigned short*)nullptr,
                      wave, lane);
    }
    tile_store(acc, bias, out, n, h0 + row_idx, o0, lane_lo, lane_hi);
    __syncthreads();   // stage(h0+4) drained; slot ring = rows h0+1..h0+4

    tile_compute<1>(acc, wA, sx, row_idx, lane_lo, lane_hi, aL);
    tile_store(acc, bias, out, n, h0 + 2 + row_idx, o0, lane_lo, lane_hi);
}

extern "C" void kernel_launch(void* const* d_in, const int* in_sizes, int n_in,
                              void* d_out, int out_size, void* d_ws, size_t ws_size,
                              hipStream_t stream) {
    const float* x    = (const float*)d_in[0];
    const float* wgt  = (const float*)d_in[1];
    const float* bias = (const float*)d_in[2];
    float* out = (float*)d_out;
    unsigned short* ws16 = (unsigned short*)d_ws;

    hipLaunchKernelGGL(xform, dim3(NIMG * HW + 288), dim3(256), 0, stream,
                       x, wgt, ws16);
    hipLaunchKernelGGL(conv_mfma, dim3(896), dim3(256), 0, stream,
                       ws16, bias, out);
}

// Round 3
// 330.836 us; speedup vs baseline: 1.1016x; 1.1016x over previous
//
#include <hip/hip_runtime.h>

#define CIN 64
#define OC 128
#define HW 112
#define HWHW (HW*HW)          // 12544
#define NIMG 32

// ws layout (elems of bf16/ushort):
//   [0, XN_ELEMS): x_nhwc bf16  [32][112][112][64]
//   [WT_OFF_EL, +73728): weights bf16, layout [tap][k-half][128 o][32 c]
#define XN_ELEMS (NIMG*HWHW*CIN)        // 25,690,112
#define WT_OFF_EL (XN_ELEMS + 128)

#define ROWE (114*64)                   // LDS row slot: 114 cols (+-1 pad) x 64c

typedef __attribute__((ext_vector_type(8))) short short8;
typedef __attribute__((ext_vector_type(4))) float floatx4;

__device__ inline unsigned short f2bf(float f) {
    unsigned u = __float_as_uint(f);
    u += 0x7fffu + ((u >> 16) & 1u);   // RNE
    return (unsigned short)(u >> 16);
}

__device__ inline void async16(const unsigned short* g, unsigned short* l) {
    __builtin_amdgcn_global_load_lds(
        (const __attribute__((address_space(1))) void*)g,
        (__attribute__((address_space(3))) void*)l, 16, 0, 0);
}

// ---- Kernel 1: x NCHW fp32 -> NHWC bf16 (LDS tile transpose), per (n,h) ----
__global__ __launch_bounds__(256) void xform_x(const float* __restrict__ x,
                                               unsigned short* __restrict__ xws)
{
    __shared__ float s[HW * (CIN + 1)];
    const int tid = threadIdx.x;
    const int n = blockIdx.x / HW;
    const int h = blockIdx.x % HW;

    const float* xp = x + (size_t)n * CIN * HWHW + h * HW;
    for (int idx = tid; idx < CIN * HW; idx += 256) {
        int c = idx / HW;
        int w = idx - c * HW;
        s[w * (CIN + 1) + c] = xp[c * HWHW + w];
    }
    __syncthreads();

    unsigned short* op = xws + ((size_t)(n * HW + h)) * HW * CIN;
    for (int idx = tid; idx < (CIN * HW) / 8; idx += 256) {
        int w  = idx >> 3;
        int c0 = (idx & 7) * 8;
        union { unsigned short us[8]; uint4 v; } u;
        #pragma unroll
        for (int j = 0; j < 8; ++j)
            u.us[j] = f2bf(s[w * (CIN + 1) + c0 + j]);
        *(uint4*)(op + w * CIN + c0) = u.v;
    }
}

// ---- Kernel 1b: weights [O][C][3][3] fp32 -> [tap][c>>5][o][c&31] bf16 ----
__global__ __launch_bounds__(256) void xform_w(const float* __restrict__ wgt,
                                               unsigned short* __restrict__ ws16)
{
    const int idx = blockIdx.x * 256 + threadIdx.x;    // 0..73727
    const int c = idx & 63;
    const int o = (idx >> 6) & 127;
    const int t = idx >> 13;                           // 0..8
    const float v = wgt[(o * CIN + c) * 9 + t];
    ws16[WT_OFF_EL + ((size_t)(t * 2 + (c >> 5)) * 128 + o) * 32 + (c & 31)] = f2bf(v);
}

// ---- Kernel 2: implicit-GEMM MFMA, x operand fully LDS-resident ----
// Block: 256 thr = 4 waves; tile 224m(2 rows) x 128o. Wave: 112m x 64o,
// MT=7, OT=4, acc[7][4] (112 AGPR). LDS: 4 x-row slots (h0-1..h0+2),
// 114 cols (pad) x 64c, XOR-swizzled c-blocks. One barrier total.
// ROUND-0 STRUCTURE (2-tile pipeline of r1/r2 regressed ~30us: extra
// barriers + half the blocks beat the free 2-block-co-residency overlap).
// Single change vs round 0: XCD-chunked bid swizzle.
__global__ __launch_bounds__(256, 2) void conv_mfma(
    const unsigned short* __restrict__ ws16,
    const float* __restrict__ bias,
    float* __restrict__ out)
{
    __shared__ unsigned short sx[4 * ROWE];   // 58368 B

    const int tid  = threadIdx.x;
    const int wave = tid >> 6;
    const int lane = tid & 63;
    const int lane_lo = lane & 15;
    const int lane_hi = lane >> 4;

    // XCD-chunked swizzle: 1792 blocks = 8 XCDs x 224; each XCD gets 224
    // consecutive tiles = exactly 4 whole images, so halo-row re-reads
    // between adjacent rp tiles hit the same XCD's L2. 1792%8==0 -> bijective.
    const int bid0 = blockIdx.x;
    const int bid  = (bid0 & 7) * 224 + (bid0 >> 3);
    const int n   = bid / 56;
    const int rp  = bid % 56;
    const int h0  = rp * 2;

    // ---- stage: wave s fills row slot s with image row h0+s-1 (or zeros) ----
    {
        const int slot = wave;
        const int hr = h0 + slot - 1;
        unsigned short* rowb = sx + slot * ROWE;
        if ((unsigned)hr < (unsigned)HW) {
            // zero the two pad columns (stored cols 0 and 113)
            if (lane < 8)        *(uint4*)(rowb + lane * 8) = (uint4){0,0,0,0};
            else if (lane < 16)  *(uint4*)(rowb + 113*64 + (lane - 8) * 8) = (uint4){0,0,0,0};
            const unsigned short* gr = ws16 + ((size_t)(n * HW + hr)) * HW * CIN;
            const int grp = lane >> 3;           // col within chunk
            const int sub = lane & 7;            // c-block slot
            // stored col ws = 1+j*8+grp -> ws&7 = (1+grp)&7; slot `sub` holds
            // logical c-block sub ^ (ws&7)
            const int swz = sub ^ ((1 + grp) & 7);
            const unsigned short* gl = gr + grp * 64 + swz * 8;
            #pragma unroll
            for (int j = 0; j < 14; ++j)
                async16(gl + j * 512, rowb + (1 + j * 8) * 64);  // uniform LDS base
        } else {
            #pragma unroll
            for (int t = 0; t < 14; ++t)
                *(uint4*)(rowb + t * 512 + lane * 8) = (uint4){0,0,0,0};
            if (lane < 16) *(uint4*)(rowb + 7168 + lane * 8) = (uint4){0,0,0,0};
        }
    }
    __syncthreads();   // compiler drains vmcnt (global_load_lds) here

    floatx4 acc[7][4];
    #pragma unroll
    for (int mt = 0; mt < 7; ++mt)
        #pragma unroll
        for (int ot = 0; ot < 4; ++ot)
            acc[mt][ot] = (floatx4){0.f, 0.f, 0.f, 0.f};

    const unsigned short* wA = ws16 + WT_OFF_EL;
    const int row_idx = wave >> 1;          // which of the 2 output rows
    const int o0 = (wave & 1) * 64;
    const int aL = (o0 + lane_lo) * 32 + lane_hi * 8;  // lane offset in [128o][32c]

    // A-frags double-buffered across taps (weights are L1/L2-hot)
    short8 a[2][2][4];
    #pragma unroll
    for (int k01 = 0; k01 < 2; ++k01)
        #pragma unroll
        for (int ot = 0; ot < 4; ++ot)
            a[0][k01][ot] = *(const short8*)(wA + k01 * 4096 + ot * 512 + aL);

    #pragma unroll
    for (int tap = 0; tap < 9; ++tap) {
        const int dh = tap / 3 - 1;
        const int dw = tap % 3 - 1;
        const int cur = tap & 1, nxt = cur ^ 1;
        if (tap < 8) {
            #pragma unroll
            for (int k01 = 0; k01 < 2; ++k01)
                #pragma unroll
                for (int ot = 0; ot < 4; ++ot)
                    a[nxt][k01][ot] = *(const short8*)(
                        wA + ((tap + 1) * 2 + k01) * 4096 + ot * 512 + aL);
        }
        const int colL = lane_lo + dw + 1;                 // stored col for mt=0
        const unsigned short* sb = sx + (row_idx + 1 + dh) * ROWE + colL * 64;
        const int sw0 = (lane_hi ^ (colL & 7)) * 8;        // k01=0 swizzle
        const int sw1 = ((lane_hi + 4) ^ (colL & 7)) * 8;  // k01=1 swizzle

        #pragma unroll
        for (int mt = 0; mt < 7; ++mt) {
            const short8 b0 = *(const short8*)(sb + mt * 1024 + sw0);
            const short8 b1 = *(const short8*)(sb + mt * 1024 + sw1);
            #pragma unroll
            for (int ot = 0; ot < 4; ++ot)
                acc[mt][ot] = __builtin_amdgcn_mfma_f32_16x16x32_bf16(
                    a[cur][0][ot], b0, acc[mt][ot], 0, 0, 0);
            #pragma unroll
            for (int ot = 0; ot < 4; ++ot)
                acc[mt][ot] = __builtin_amdgcn_mfma_f32_16x16x32_bf16(
                    a[cur][1][ot], b1, acc[mt][ot], 0, 0, 0);
        }
    }

    // ---- epilogue: D col = m (lane_lo), row = o_rel = lane_hi*4 + i ----
    const int h = h0 + row_idx;
    #pragma unroll
    for (int ot = 0; ot < 4; ++ot) {
        const int ob = o0 + ot * 16 + lane_hi * 4;
        const float4 bv = *(const float4*)(bias + ob);
        #pragma unroll
        for (int mt = 0; mt < 7; ++mt) {
            const int w = mt * 16 + lane_lo;
            float* op = out + ((size_t)(n * OC + ob) * HW + h) * HW + w;
            op[0]        = acc[mt][ot].x + bv.x;
            op[HWHW]     = acc[mt][ot].y + bv.y;
            op[2 * HWHW] = acc[mt][ot].z + bv.z;
            op[3 * HWHW] = acc[mt][ot].w + bv.w;
        }
    }
}

extern "C" void kernel_launch(void* const* d_in, const int* in_sizes, int n_in,
                              void* d_out, int out_size, void* d_ws, size_t ws_size,
                              hipStream_t stream) {
    const float* x    = (const float*)d_in[0];
    const float* wgt  = (const float*)d_in[1];
    const float* bias = (const float*)d_in[2];
    float* out = (float*)d_out;
    unsigned short* ws16 = (unsigned short*)d_ws;

    hipLaunchKernelGGL(xform_x, dim3(NIMG * HW), dim3(256), 0, stream, x, ws16);
    hipLaunchKernelGGL(xform_w, dim3(288), dim3(256), 0, stream, wgt, ws16);
    hipLaunchKernelGGL(conv_mfma, dim3(NIMG * 56), dim3(256), 0, stream,
                       ws16, bias, out);
}